// Round 2
// baseline (490.231 us; speedup 1.0000x reference)
//
#include <hip/hip_runtime.h>

#define B_ 2
#define L_ 4096
#define D_ 512
#define H_ 8
#define E_ 64
#define M_ (B_*L_)        // 8192 rows
#define TD (3*D_)         // 1536
#define NCH (L_/64)       // 64 chunks of 64 per sequence
#define BH (B_*H_)        // 16

// ---------------- K1a: decay logits -> log(lambda) per (b,h,l) ----------------
__global__ __launch_bounds__(64) void decay_ll_kernel(const float* __restrict__ x,
    const float* __restrict__ dw, const float* __restrict__ db, float* __restrict__ ll)
{
  int m = blockIdx.x;                 // b*L + l
  int lane = threadIdx.x;
  float xr[8];
  #pragma unroll
  for (int i=0;i<8;i++) xr[i] = x[(size_t)m*D_ + lane + 64*i];
  int b = m >> 12, l = m & (L_-1);
  for (int h=0; h<H_; h++){
    float acc = 0.f;
    #pragma unroll
    for (int i=0;i<8;i++) acc += xr[i]*dw[h*D_ + lane + 64*i];
    #pragma unroll
    for (int off=32; off>0; off>>=1) acc += __shfl_xor(acc, off);
    if (lane == h){
      float z = acc + db[h];
      float lam = 0.9f + 0.1f/(1.f + expf(-z));   // *PLASTICITY(=1)
      ll[((b*H_+h)*L_) + l] = logf(lam);          // lam>0.9 so clip(1e-6) is no-op
    }
  }
}

// ---------------- K1b: inclusive scan over L, clip to [-50,50] ----------------
__global__ __launch_bounds__(1024) void scan_kernel(const float* __restrict__ ll,
    float* __restrict__ cb)
{
  int bh = blockIdx.x, t = threadIdx.x;
  __shared__ float part[1024];
  const float* p = ll + (size_t)bh*L_ + t*4;
  float v0=p[0], v1=p[1], v2=p[2], v3=p[3];
  float l0=v0, s1=v0+v1, s2=s1+v2, s3=s2+v3;
  part[t]=s3; __syncthreads();
  float sum = s3;
  for (int st=1; st<1024; st<<=1){
    float tv = (t>=st)? part[t-st] : 0.f;
    __syncthreads();
    sum += tv; part[t]=sum;
    __syncthreads();
  }
  float ex = sum - s3;
  float* c = cb + (size_t)bh*L_ + t*4;
  c[0]=fminf(50.f,fmaxf(-50.f,ex+l0));
  c[1]=fminf(50.f,fmaxf(-50.f,ex+s1));
  c[2]=fminf(50.f,fmaxf(-50.f,ex+s2));
  c[3]=fminf(50.f,fmaxf(-50.f,ex+s3));
}

// ---------------- GEMM: C[m][n] = sum_k A[m][k]*W[n][k] + bias[n] ----------------
// 128x128 tile, BK=8, 256 threads, 8x8 per thread (fp32 VALU; MFMA in a later round)
__global__ __launch_bounds__(256) void gemm_nt(const float* __restrict__ A,
    const float* __restrict__ W, const float* __restrict__ bias,
    float* __restrict__ C, int M, int N, int K)
{
  __shared__ float As[8][128];
  __shared__ float Bs[8][128];
  int n0 = blockIdx.x*128, m0 = blockIdx.y*128;
  int t = threadIdx.x;
  int tx = t & 15, ty = t >> 4;
  int lm = t >> 1, lk = (t & 1)*4;
  float acc[8][8] = {};
  for (int k0=0; k0<K; k0+=8){
    float4 av = *(const float4*)(A + (size_t)(m0+lm)*K + k0+lk);
    float4 bv = *(const float4*)(W + (size_t)(n0+lm)*K + k0+lk);
    As[lk+0][lm]=av.x; As[lk+1][lm]=av.y; As[lk+2][lm]=av.z; As[lk+3][lm]=av.w;
    Bs[lk+0][lm]=bv.x; Bs[lk+1][lm]=bv.y; Bs[lk+2][lm]=bv.z; Bs[lk+3][lm]=bv.w;
    __syncthreads();
    #pragma unroll
    for (int kk=0;kk<8;kk++){
      float a[8], b[8];
      *(float4*)&a[0] = *(const float4*)&As[kk][ty*8];
      *(float4*)&a[4] = *(const float4*)&As[kk][ty*8+4];
      *(float4*)&b[0] = *(const float4*)&Bs[kk][tx*8];
      *(float4*)&b[4] = *(const float4*)&Bs[kk][tx*8+4];
      #pragma unroll
      for (int i=0;i<8;i++)
        #pragma unroll
        for (int j=0;j<8;j++) acc[i][j] += a[i]*b[j];
    }
    __syncthreads();
  }
  #pragma unroll
  for (int i=0;i<8;i++){
    int row = m0 + ty*8 + i;
    float ov[8];
    #pragma unroll
    for (int j=0;j<8;j++) ov[j] = acc[i][j] + bias[n0+tx*8+j];
    *(float4*)&C[(size_t)row*N + n0 + tx*8]     = *(float4*)&ov[0];
    *(float4*)&C[(size_t)row*N + n0 + tx*8 + 4] = *(float4*)&ov[4];
  }
}

// ---------------- K3: apply elu+1 and decay scaling in place ----------------
// q~ = (elu(q)+1)/8 * exp(c);  k~ = (elu(k)+1) * exp(-c);  v untouched
__global__ __launch_bounds__(256) void transform_kernel(float* __restrict__ qkv,
    const float* __restrict__ cb)
{
  int idx = blockIdx.x*256 + threadIdx.x;     // covers M_*1024 exactly
  int m = idx >> 10, p = idx & 1023;
  int b = m >> 12, l = m & (L_-1);
  bool isq = p < 512;
  int col = isq ? p : (p-512);
  int h = col >> 6;
  float c = cb[((b*H_+h)*L_) + l];
  size_t off = (size_t)m*TD + (isq ? (size_t)col : (size_t)(D_ + col));
  float v = qkv[off];
  float e = (v > 0.f) ? (v + 1.f) : expf(v);  // elu(x)+1
  qkv[off] = isq ? (e*0.125f*expf(c)) : (e*expf(-c));
}

// ---------------- K4: per-chunk sums S_c = sum_j k~_j (x) v_j, ksum_c ----------------
__global__ __launch_bounds__(256) void chunk_sums_kernel(const float* __restrict__ qkv,
    float* __restrict__ Sc, float* __restrict__ ksc)
{
  int bid = blockIdx.x;               // bh*NCH + chunk
  int bh = bid >> 6, chunk = bid & 63;
  int b = bh >> 3, h = bh & 7;
  __shared__ float Ks[4096], Vs[4096];
  int t = threadIdx.x;
  size_t mbase = (size_t)b*L_ + chunk*64;
  #pragma unroll
  for (int i=0;i<16;i++){
    int idx = t + 256*i; int l = idx>>6, e = idx&63;
    const float* row = qkv + (mbase+l)*TD + h*64 + e;
    Ks[idx] = row[D_];
    Vs[idx] = row[2*D_];
  }
  __syncthreads();
  int e = t & 63, fb = (t>>6)*16;
  float acc[16] = {};
  float ks = 0.f;
  for (int j=0;j<64;j++){
    float kv = Ks[j*64+e];
    ks += kv;
    #pragma unroll
    for (int i=0;i<16;i++) acc[i] += kv*Vs[j*64+fb+i];
  }
  float* S = Sc + (size_t)bid*4096;
  #pragma unroll
  for (int i=0;i<16;i++) S[e*64+fb+i] = acc[i];
  if (t < 64) ksc[bid*64 + e] = ks;
}

// ---------------- K5: exclusive prefix over chunks (in place) ----------------
__global__ __launch_bounds__(256) void chunk_prefix_kernel(float* __restrict__ Sc,
    float* __restrict__ ksc)
{
  int bh = blockIdx.x, t = threadIdx.x;
  float run[16];
  #pragma unroll
  for (int i=0;i<16;i++) run[i]=0.f;
  float kr = 0.f;
  for (int ch=0; ch<NCH; ch++){
    float* S = Sc + ((size_t)bh*NCH + ch)*4096 + t*16;
    #pragma unroll
    for (int i=0;i<16;i++){ float tmp=S[i]; S[i]=run[i]; run[i]+=tmp; }
    if (t < 64){
      float* kp = ksc + ((bh*NCH+ch)*64) + t;
      float tmp = *kp; *kp = kr; kr += tmp;
    }
  }
}

// ---------------- K6: per-chunk output: num = Q~ S_prefix + tril(Q~K~^T) V ----------------
__global__ __launch_bounds__(256) void chunk_out_kernel(const float* __restrict__ qkv,
    const float* __restrict__ Sc, const float* __restrict__ ksc,
    float* __restrict__ attn)
{
  int bid = blockIdx.x;
  int bh = bid >> 6, chunk = bid & 63;
  int b = bh >> 3, h = bh & 7;
  __shared__ float Qt[4096];   // Qt[e*64+l]  (transposed -> conflict-free reads)
  __shared__ float KA[4096];   // Kt[e*64+j] then At[j*64+l]
  __shared__ float Vs[4096];   // Vs[j*64+f]
  __shared__ float Ss[4096];   // Ss[e*64+f]  (prefix state)
  int t = threadIdx.x;
  size_t mbase = (size_t)b*L_ + chunk*64;
  const float* Sp = Sc + (size_t)bid*4096;
  #pragma unroll
  for (int i=0;i<16;i++){
    int idx = t + 256*i; int r = idx>>6, cix = idx&63;
    const float* row = qkv + (mbase+r)*TD + h*64 + cix;
    Qt[cix*64 + r] = row[0];
    KA[cix*64 + r] = row[D_];
    Vs[idx]        = row[2*D_];
    Ss[idx]        = Sp[idx];
  }
  __syncthreads();
  int l = t >> 2, jb = (t & 3)*16;
  // A[l][j] = sum_e q~[l][e] k~[j][e]
  float a[16] = {};
  for (int e=0; e<64; e++){
    float qv = Qt[e*64 + l];
    #pragma unroll
    for (int i=0;i<16;i++) a[i] += qv * KA[e*64 + jb + i];
  }
  __syncthreads();   // all reads of Kt done before overwrite
  #pragma unroll
  for (int i=0;i<16;i++) KA[(jb+i)*64 + l] = (jb+i <= l) ? a[i] : 0.f;
  __syncthreads();
  // num + den
  const float* kp = ksc + bid*64;   // exclusive chunk prefix of k~ sums
  int fb = jb;
  float acc[16] = {};
  float den = 0.f;
  for (int e=0;e<64;e++){
    float qv = Qt[e*64 + l];
    den += qv * kp[e];
    #pragma unroll
    for (int i=0;i<16;i++) acc[i] += qv * Ss[e*64 + fb + i];
  }
  for (int j=0;j<64;j++){
    float av = KA[j*64 + l];       // zero for j>l
    den += av;
    #pragma unroll
    for (int i=0;i<16;i++) acc[i] += av * Vs[j*64 + fb + i];
  }
  float inv = 1.f/(den + 1e-6f);
  float* orow = attn + (mbase + l)*D_ + h*64 + fb;
  #pragma unroll
  for (int i=0;i<16;i++) orow[i] = acc[i]*inv;
}

// ---------------- K8: RMSNorm + scale ----------------
__global__ __launch_bounds__(256) void rmsnorm_kernel(const float* __restrict__ mid,
    const float* __restrict__ scale, float* __restrict__ out)
{
  int m = blockIdx.x, t = threadIdx.x;
  const float* row = mid + (size_t)m*D_;
  float v0 = row[t], v1 = row[t+256];
  float ss = v0*v0 + v1*v1;
  #pragma unroll
  for (int off=32; off>0; off>>=1) ss += __shfl_xor(ss, off);
  __shared__ float red[4];
  if ((t&63)==0) red[t>>6] = ss;
  __syncthreads();
  float tot = red[0]+red[1]+red[2]+red[3];
  float r = rsqrtf(tot*(1.f/512.f) + 1e-8f);
  out[(size_t)m*D_ + t]       = v0*r*scale[t];
  out[(size_t)m*D_ + t + 256] = v1*r*scale[t+256];
}

extern "C" void kernel_launch(void* const* d_in, const int* in_sizes, int n_in,
                              void* d_out, int out_size, void* d_ws, size_t ws_size,
                              hipStream_t stream)
{
  const float* x  = (const float*)d_in[0];
  const float* qw = (const float*)d_in[1];
  const float* qb = (const float*)d_in[2];
  const float* ow = (const float*)d_in[3];
  const float* ob = (const float*)d_in[4];
  const float* dw = (const float*)d_in[5];
  const float* db = (const float*)d_in[6];
  const float* ns = (const float*)d_in[7];
  float* out = (float*)d_out;

  char* ws = (char*)d_ws;
  // layout (bytes): qkv fp32 [M,1536] | ll | c | Sc | ksc | attn ; mid reuses qkv
  float* qkv  = (float*)(ws);                  // 50,331,648
  float* ll   = (float*)(ws + 50331648);       //    262,144
  float* cb   = (float*)(ws + 50593792);       //    262,144
  float* Sc   = (float*)(ws + 50855936);       // 16,777,216
  float* ksc  = (float*)(ws + 67633152);       //    262,144
  float* attn = (float*)(ws + 67895296);       // 16,777,216  (total 84,672,512 B)
  float* mid  = qkv;                           // reuse after chunk_out

  decay_ll_kernel<<<dim3(M_), dim3(64), 0, stream>>>(x, dw, db, ll);
  scan_kernel<<<dim3(BH), dim3(1024), 0, stream>>>(ll, cb);
  gemm_nt<<<dim3(TD/128, M_/128), dim3(256), 0, stream>>>(x, qw, qb, qkv, M_, TD, D_);
  transform_kernel<<<dim3(M_*1024/256), dim3(256), 0, stream>>>(qkv, cb);
  chunk_sums_kernel<<<dim3(BH*NCH), dim3(256), 0, stream>>>(qkv, Sc, ksc);
  chunk_prefix_kernel<<<dim3(BH), dim3(256), 0, stream>>>(Sc, ksc);
  chunk_out_kernel<<<dim3(BH*NCH), dim3(256), 0, stream>>>(qkv, Sc, ksc, attn);
  gemm_nt<<<dim3(D_/128, M_/128), dim3(256), 0, stream>>>(attn, ow, ob, qkv, M_, D_, D_);
  rmsnorm_kernel<<<dim3(M_), dim3(256), 0, stream>>>(qkv, ns, out);
}

// Round 3
// 235.102 us; speedup vs baseline: 2.0852x; 2.0852x over previous
//
#include <hip/hip_runtime.h>

typedef unsigned short u16;
typedef unsigned int u32;

#define B_ 2
#define L_ 4096
#define D_ 512
#define H_ 8
#define E_ 64
#define M_ (B_*L_)        // 8192 rows
#define TD (3*D_)         // 1536
#define NCH (L_/64)       // 64 chunks of 64 per sequence
#define BH (B_*H_)        // 16

typedef short bf16x8 __attribute__((ext_vector_type(8)));
typedef float f32x4 __attribute__((ext_vector_type(4)));

__device__ __forceinline__ u16 f2bf(float f){
  u32 u = __float_as_uint(f);
  u32 r = u + 0x7FFFu + ((u>>16)&1u);   // RNE; inputs finite
  return (u16)(r>>16);
}

__device__ __forceinline__ void async_ld16(const u16* g, u16* l){
  __builtin_amdgcn_global_load_lds(
      (const __attribute__((address_space(1))) void*)g,
      (__attribute__((address_space(3))) void*)l, 16, 0, 0);
}

// ---------------- K0: fp32 -> bf16 conversions (x, qkv_w, out_w) ----------------
// float4-sized segments: x 1048576, qw 196608, ow 65536  (total 1310720 -> 5120 blocks)
__global__ __launch_bounds__(256) void convert_kernel(const float* __restrict__ x,
    const float* __restrict__ qw, const float* __restrict__ ow,
    u16* __restrict__ xb, u16* __restrict__ qwb, u16* __restrict__ owb)
{
  int gid = blockIdx.x*256 + threadIdx.x;
  const float* src; u16* dst; int off;
  if (gid < 1048576){ src = x; dst = xb; off = gid; }
  else if (gid < 1048576+196608){ src = qw; dst = qwb; off = gid - 1048576; }
  else { src = ow; dst = owb; off = gid - 1048576 - 196608; }
  float4 v = ((const float4*)src)[off];
  ushort4 o; o.x=f2bf(v.x); o.y=f2bf(v.y); o.z=f2bf(v.z); o.w=f2bf(v.w);
  ((ushort4*)dst)[off] = o;
}

// ---------------- K1a: decay logits -> log(lambda) per (b,h,l) ----------------
__global__ __launch_bounds__(64) void decay_ll_kernel(const float* __restrict__ x,
    const float* __restrict__ dw, const float* __restrict__ db, float* __restrict__ ll)
{
  int m = blockIdx.x;                 // b*L + l
  int lane = threadIdx.x;
  float xr[8];
  #pragma unroll
  for (int i=0;i<8;i++) xr[i] = x[(size_t)m*D_ + lane + 64*i];
  int b = m >> 12, l = m & (L_-1);
  for (int h=0; h<H_; h++){
    float acc = 0.f;
    #pragma unroll
    for (int i=0;i<8;i++) acc += xr[i]*dw[h*D_ + lane + 64*i];
    #pragma unroll
    for (int off=32; off>0; off>>=1) acc += __shfl_xor(acc, off);
    if (lane == h){
      float z = acc + db[h];
      float lam = 0.9f + 0.1f/(1.f + expf(-z));   // *PLASTICITY(=1)
      ll[((b*H_+h)*L_) + l] = logf(lam);          // lam>0.9 so clip(1e-6) is no-op
    }
  }
}

// ---------------- K1b: inclusive scan over L, clip to [-50,50] ----------------
__global__ __launch_bounds__(1024) void scan_kernel(const float* __restrict__ ll,
    float* __restrict__ cb)
{
  int bh = blockIdx.x, t = threadIdx.x;
  __shared__ float part[1024];
  const float* p = ll + (size_t)bh*L_ + t*4;
  float v0=p[0], v1=p[1], v2=p[2], v3=p[3];
  float l0=v0, s1=v0+v1, s2=s1+v2, s3=s2+v3;
  part[t]=s3; __syncthreads();
  float sum = s3;
  for (int st=1; st<1024; st<<=1){
    float tv = (t>=st)? part[t-st] : 0.f;
    __syncthreads();
    sum += tv; part[t]=sum;
    __syncthreads();
  }
  float ex = sum - s3;
  float* c = cb + (size_t)bh*L_ + t*4;
  c[0]=fminf(50.f,fmaxf(-50.f,ex+l0));
  c[1]=fminf(50.f,fmaxf(-50.f,ex+s1));
  c[2]=fminf(50.f,fmaxf(-50.f,ex+s2));
  c[3]=fminf(50.f,fmaxf(-50.f,ex+s3));
}

// ---------------- MFMA GEMM: C[m][n] = sum_k A[m][k]*W[n][k] + bias[n] ----------------
// bf16 inputs, fp32 accumulate. 128x128 tile, BK=32, 4 waves, 4x4 MFMA 16x16x32 per wave.
// Staging via global_load_lds width=16 (wave-uniform base + lane*16).
__global__ __launch_bounds__(256) void gemm_mfma(const u16* __restrict__ A,
    const u16* __restrict__ W, const float* __restrict__ bias,
    float* __restrict__ C, int M, int N, int K)
{
  __shared__ u16 As[128*32];
  __shared__ u16 Bs[128*32];
  int n0 = blockIdx.x*128, m0 = blockIdx.y*128;
  int t = threadIdx.x, wave = t>>6, lane = t&63;
  int wm = (wave>>1)*64, wn = (wave&1)*64;
  f32x4 acc[4][4] = {};
  // staging: wave w covers rows w*32..w*32+31 in two 16-row issues
  int srow = wave*32 + (lane>>2);
  int scol = (lane&3)*8;
  const u16* gA = A + (size_t)(m0+srow)*K + scol;
  const u16* gB = W + (size_t)(n0+srow)*K + scol;
  u16* lA = As + wave*1024;
  u16* lB = Bs + wave*1024;
  int q8 = (lane>>4)*8, r16 = lane&15;
  for (int k0=0; k0<K; k0+=32){
    async_ld16(gA + k0,            lA);
    async_ld16(gA + k0 + 16*(size_t)K, lA + 512);
    async_ld16(gB + k0,            lB);
    async_ld16(gB + k0 + 16*(size_t)K, lB + 512);
    __syncthreads();
    bf16x8 af[4], bfr[4];
    #pragma unroll
    for (int i=0;i<4;i++) af[i]  = *(const bf16x8*)&As[(wm + i*16 + r16)*32 + q8];
    #pragma unroll
    for (int j=0;j<4;j++) bfr[j] = *(const bf16x8*)&Bs[(wn + j*16 + r16)*32 + q8];
    #pragma unroll
    for (int i=0;i<4;i++)
      #pragma unroll
      for (int j=0;j<4;j++)
        acc[i][j] = __builtin_amdgcn_mfma_f32_16x16x32_bf16(af[i], bfr[j], acc[i][j], 0,0,0);
    __syncthreads();
  }
  // epilogue: D row = (lane>>4)*4 + reg (A's m), col = lane&15 (B's n)
  #pragma unroll
  for (int i=0;i<4;i++){
    int row = m0 + wm + i*16 + (lane>>4)*4;
    #pragma unroll
    for (int j=0;j<4;j++){
      int col = n0 + wn + j*16 + r16;
      float bv = bias[col];
      #pragma unroll
      for (int r=0;r<4;r++)
        C[(size_t)(row+r)*N + col] = acc[i][j][r] + bv;
    }
  }
}

// ---------------- K3: apply elu+1 and decay scaling in place ----------------
// q~ = (elu(q)+1)/8 * exp(c);  k~ = (elu(k)+1) * exp(-c);  v untouched
__global__ __launch_bounds__(256) void transform_kernel(float* __restrict__ qkv,
    const float* __restrict__ cb)
{
  int idx = blockIdx.x*256 + threadIdx.x;     // covers M_*1024 exactly
  int m = idx >> 10, p = idx & 1023;
  int b = m >> 12, l = m & (L_-1);
  bool isq = p < 512;
  int col = isq ? p : (p-512);
  int h = col >> 6;
  float c = cb[((b*H_+h)*L_) + l];
  size_t off = (size_t)m*TD + (isq ? (size_t)col : (size_t)(D_ + col));
  float v = qkv[off];
  float e = (v > 0.f) ? (v + 1.f) : expf(v);  // elu(x)+1
  qkv[off] = isq ? (e*0.125f*expf(c)) : (e*expf(-c));
}

// ---------------- K4: per-chunk sums S_c = sum_j k~_j (x) v_j, ksum_c ----------------
__global__ __launch_bounds__(256) void chunk_sums_kernel(const float* __restrict__ qkv,
    float* __restrict__ Sc, float* __restrict__ ksc)
{
  int bid = blockIdx.x;               // bh*NCH + chunk
  int bh = bid >> 6, chunk = bid & 63;
  int b = bh >> 3, h = bh & 7;
  __shared__ float Ks[4096], Vs[4096];
  int t = threadIdx.x;
  size_t mbase = (size_t)b*L_ + chunk*64;
  #pragma unroll
  for (int i=0;i<16;i++){
    int idx = t + 256*i; int l = idx>>6, e = idx&63;
    const float* row = qkv + (mbase+l)*TD + h*64 + e;
    Ks[idx] = row[D_];
    Vs[idx] = row[2*D_];
  }
  __syncthreads();
  int e = t & 63, fb = (t>>6)*16;
  float acc[16] = {};
  float ks = 0.f;
  for (int j=0;j<64;j++){
    float kv = Ks[j*64+e];
    ks += kv;
    #pragma unroll
    for (int i=0;i<16;i++) acc[i] += kv*Vs[j*64+fb+i];
  }
  float* S = Sc + (size_t)bid*4096;
  #pragma unroll
  for (int i=0;i<16;i++) S[e*64+fb+i] = acc[i];
  if (t < 64) ksc[bid*64 + e] = ks;
}

// ---------------- K5: exclusive prefix over chunks — 65536 parallel lanes ----------------
__global__ __launch_bounds__(256) void chunk_prefix_kernel(float* __restrict__ Sc,
    float* __restrict__ ksc)
{
  int gid = blockIdx.x*256 + threadIdx.x;   // 65536 threads (256 blocks)
  int bh = gid >> 12, elem = gid & 4095;
  float run = 0.f;
  float* p = Sc + ((size_t)bh*NCH)*4096 + elem;
  for (int ch=0; ch<NCH; ch++){
    float v = p[(size_t)ch*4096];
    p[(size_t)ch*4096] = run;
    run += v;
  }
  if (gid < BH*64){
    int bh2 = gid >> 6, e = gid & 63;
    float kr = 0.f;
    float* kp = ksc + bh2*NCH*64 + e;
    for (int ch=0; ch<NCH; ch++){ float v = kp[ch*64]; kp[ch*64] = kr; kr += v; }
  }
}

// ---------------- K6: per-chunk output: num = Q~ S_prefix + tril(Q~K~^T) V ----------------
// writes attn as bf16 for the MFMA out-projection
__global__ __launch_bounds__(256) void chunk_out_kernel(const float* __restrict__ qkv,
    const float* __restrict__ Sc, const float* __restrict__ ksc,
    u16* __restrict__ attn)
{
  int bid = blockIdx.x;
  int bh = bid >> 6, chunk = bid & 63;
  int b = bh >> 3, h = bh & 7;
  __shared__ float Qt[4096];   // Qt[e*64+l]
  __shared__ float KA[4096];   // Kt[e*64+j] then At[j*64+l]
  __shared__ float Vs[4096];   // Vs[j*64+f]
  __shared__ float Ss[4096];   // Ss[e*64+f]  (prefix state)
  int t = threadIdx.x;
  size_t mbase = (size_t)b*L_ + chunk*64;
  const float* Sp = Sc + (size_t)bid*4096;
  #pragma unroll
  for (int i=0;i<16;i++){
    int idx = t + 256*i; int r = idx>>6, cix = idx&63;
    const float* row = qkv + (mbase+r)*TD + h*64 + cix;
    Qt[cix*64 + r] = row[0];
    KA[cix*64 + r] = row[D_];
    Vs[idx]        = row[2*D_];
    Ss[idx]        = Sp[idx];
  }
  __syncthreads();
  int l = t >> 2, jb = (t & 3)*16;
  float a[16] = {};
  for (int e=0; e<64; e++){
    float qv = Qt[e*64 + l];
    #pragma unroll
    for (int i=0;i<16;i++) a[i] += qv * KA[e*64 + jb + i];
  }
  __syncthreads();
  #pragma unroll
  for (int i=0;i<16;i++) KA[(jb+i)*64 + l] = (jb+i <= l) ? a[i] : 0.f;
  __syncthreads();
  const float* kp = ksc + bid*64;
  int fb = jb;
  float acc[16] = {};
  float den = 0.f;
  for (int e=0;e<64;e++){
    float qv = Qt[e*64 + l];
    den += qv * kp[e];
    #pragma unroll
    for (int i=0;i<16;i++) acc[i] += qv * Ss[e*64 + fb + i];
  }
  for (int j=0;j<64;j++){
    float av = KA[j*64 + l];       // zero for j>l
    den += av;
    #pragma unroll
    for (int i=0;i<16;i++) acc[i] += av * Vs[j*64 + fb + i];
  }
  float inv = 1.f/(den + 1e-6f);
  u16* orow = attn + (mbase + l)*D_ + h*64 + fb;
  #pragma unroll
  for (int i=0;i<16;i++) orow[i] = f2bf(acc[i]*inv);
}

// ---------------- K8: RMSNorm + scale ----------------
__global__ __launch_bounds__(256) void rmsnorm_kernel(const float* __restrict__ mid,
    const float* __restrict__ scale, float* __restrict__ out)
{
  int m = blockIdx.x, t = threadIdx.x;
  const float* row = mid + (size_t)m*D_;
  float v0 = row[t], v1 = row[t+256];
  float ss = v0*v0 + v1*v1;
  #pragma unroll
  for (int off=32; off>0; off>>=1) ss += __shfl_xor(ss, off);
  __shared__ float red[4];
  if ((t&63)==0) red[t>>6] = ss;
  __syncthreads();
  float tot = red[0]+red[1]+red[2]+red[3];
  float r = rsqrtf(tot*(1.f/512.f) + 1e-8f);
  out[(size_t)m*D_ + t]       = v0*r*scale[t];
  out[(size_t)m*D_ + t + 256] = v1*r*scale[t+256];
}

extern "C" void kernel_launch(void* const* d_in, const int* in_sizes, int n_in,
                              void* d_out, int out_size, void* d_ws, size_t ws_size,
                              hipStream_t stream)
{
  const float* x  = (const float*)d_in[0];
  const float* qw = (const float*)d_in[1];
  const float* qb = (const float*)d_in[2];
  const float* ow = (const float*)d_in[3];
  const float* ob = (const float*)d_in[4];
  const float* dw = (const float*)d_in[5];
  const float* db = (const float*)d_in[6];
  const float* ns = (const float*)d_in[7];
  float* out = (float*)d_out;

  char* ws = (char*)d_ws;
  float* qkv  = (float*)(ws);                  // 50,331,648  (mid reuses)
  float* ll   = (float*)(ws + 50331648);       //    262,144
  float* cb   = (float*)(ws + 50593792);       //    262,144
  float* Sc   = (float*)(ws + 50855936);       // 16,777,216
  float* ksc  = (float*)(ws + 67633152);       //    262,144
  u16*   xb   = (u16*)  (ws + 67895296);       //  8,388,608  (attn bf16 reuses: xb dead after QKV gemm)
  u16*   attn = (u16*)  (ws + 67895296);
  u16*   qwb  = (u16*)  (ws + 76283904);       //  1,572,864
  u16*   owb  = (u16*)  (ws + 77856768);       //    524,288   total 78,381,056 B
  float* mid  = qkv;

  convert_kernel<<<dim3(5120), dim3(256), 0, stream>>>(x, qw, ow, xb, qwb, owb);
  decay_ll_kernel<<<dim3(M_), dim3(64), 0, stream>>>(x, dw, db, ll);
  scan_kernel<<<dim3(BH), dim3(1024), 0, stream>>>(ll, cb);
  gemm_mfma<<<dim3(TD/128, M_/128), dim3(256), 0, stream>>>(xb, qwb, qb, qkv, M_, TD, D_);
  transform_kernel<<<dim3(M_*1024/256), dim3(256), 0, stream>>>(qkv, cb);
  chunk_sums_kernel<<<dim3(BH*NCH), dim3(256), 0, stream>>>(qkv, Sc, ksc);
  chunk_prefix_kernel<<<dim3(256), dim3(256), 0, stream>>>(Sc, ksc);
  chunk_out_kernel<<<dim3(BH*NCH), dim3(256), 0, stream>>>(qkv, Sc, ksc, attn);
  gemm_mfma<<<dim3(D_/128, M_/128), dim3(256), 0, stream>>>(attn, owb, ob, mid, M_, D_, D_);
  rmsnorm_kernel<<<dim3(M_), dim3(256), 0, stream>>>(mid, ns, out);
}

// Round 4
// 185.471 us; speedup vs baseline: 2.6432x; 1.2676x over previous
//
#include <hip/hip_runtime.h>

typedef unsigned short u16;
typedef unsigned int u32;

#define B_ 2
#define L_ 4096
#define D_ 512
#define H_ 8
#define E_ 64
#define M_ (B_*L_)        // 8192 rows
#define TD (3*D_)         // 1536
#define NCH (L_/64)       // 64 chunks of 64 per sequence
#define BH (B_*H_)        // 16

typedef short bf16x8 __attribute__((ext_vector_type(8)));
typedef float f32x4 __attribute__((ext_vector_type(4)));

__device__ __forceinline__ float bf2f(u16 u){ return __uint_as_float(((u32)u)<<16); }
__device__ __forceinline__ u16 f2bf(float f){
  u32 u = __float_as_uint(f);
  u32 r = u + 0x7FFFu + ((u>>16)&1u);   // RNE; inputs finite
  return (u16)(r>>16);
}
__device__ __forceinline__ float elu1(float v){ return v>0.f ? v+1.f : expf(v); }

__device__ __forceinline__ void async_ld16(const u16* g, u16* l){
  __builtin_amdgcn_global_load_lds(
      (const __attribute__((address_space(1))) void*)g,
      (__attribute__((address_space(3))) void*)l, 16, 0, 0);
}

// ---------------- K0: fp32 -> bf16 conversions (x, qkv_w, out_w) ----------------
__global__ __launch_bounds__(256) void convert_kernel(const float* __restrict__ x,
    const float* __restrict__ qw, const float* __restrict__ ow,
    u16* __restrict__ xb, u16* __restrict__ qwb, u16* __restrict__ owb)
{
  int gid = blockIdx.x*256 + threadIdx.x;
  const float* src; u16* dst; int off;
  if (gid < 1048576){ src = x; dst = xb; off = gid; }
  else if (gid < 1048576+196608){ src = qw; dst = qwb; off = gid - 1048576; }
  else { src = ow; dst = owb; off = gid - 1048576 - 196608; }
  float4 v = ((const float4*)src)[off];
  ushort4 o; o.x=f2bf(v.x); o.y=f2bf(v.y); o.z=f2bf(v.z); o.w=f2bf(v.w);
  ((ushort4*)dst)[off] = o;
}

// ---------------- K1a: decay logits -> log(lambda) per (b,h,l) ----------------
__global__ __launch_bounds__(64) void decay_ll_kernel(const float* __restrict__ x,
    const float* __restrict__ dw, const float* __restrict__ db, float* __restrict__ ll)
{
  int m = blockIdx.x;
  int lane = threadIdx.x;
  float xr[8];
  #pragma unroll
  for (int i=0;i<8;i++) xr[i] = x[(size_t)m*D_ + lane + 64*i];
  int b = m >> 12, l = m & (L_-1);
  for (int h=0; h<H_; h++){
    float acc = 0.f;
    #pragma unroll
    for (int i=0;i<8;i++) acc += xr[i]*dw[h*D_ + lane + 64*i];
    #pragma unroll
    for (int off=32; off>0; off>>=1) acc += __shfl_xor(acc, off);
    if (lane == h){
      float z = acc + db[h];
      float lam = 0.9f + 0.1f/(1.f + expf(-z));
      ll[((b*H_+h)*L_) + l] = logf(lam);
    }
  }
}

// ---------------- K1b: inclusive scan over L, clip to [-50,50] ----------------
__global__ __launch_bounds__(1024) void scan_kernel(const float* __restrict__ ll,
    float* __restrict__ cb)
{
  int bh = blockIdx.x, t = threadIdx.x;
  __shared__ float part[1024];
  const float* p = ll + (size_t)bh*L_ + t*4;
  float v0=p[0], v1=p[1], v2=p[2], v3=p[3];
  float l0=v0, s1=v0+v1, s2=s1+v2, s3=s2+v3;
  part[t]=s3; __syncthreads();
  float sum = s3;
  for (int st=1; st<1024; st<<=1){
    float tv = (t>=st)? part[t-st] : 0.f;
    __syncthreads();
    sum += tv; part[t]=sum;
    __syncthreads();
  }
  float ex = sum - s3;
  float* c = cb + (size_t)bh*L_ + t*4;
  c[0]=fminf(50.f,fmaxf(-50.f,ex+l0));
  c[1]=fminf(50.f,fmaxf(-50.f,ex+s1));
  c[2]=fminf(50.f,fmaxf(-50.f,ex+s2));
  c[3]=fminf(50.f,fmaxf(-50.f,ex+s3));
}

// ---------------- MFMA GEMM: C[m][n] = sum_k A[m][k]*W[n][k] + bias[n] ----------------
template<bool OB>
__global__ __launch_bounds__(256) void gemm_mfma(const u16* __restrict__ A,
    const u16* __restrict__ W, const float* __restrict__ bias,
    void* __restrict__ Cv, int M, int N, int K)
{
  __shared__ u16 As[128*32];
  __shared__ u16 Bs[128*32];
  int n0 = blockIdx.x*128, m0 = blockIdx.y*128;
  int t = threadIdx.x, wave = t>>6, lane = t&63;
  int wm = (wave>>1)*64, wn = (wave&1)*64;
  f32x4 acc[4][4] = {};
  int srow = wave*32 + (lane>>2);
  int scol = (lane&3)*8;
  const u16* gA = A + (size_t)(m0+srow)*K + scol;
  const u16* gB = W + (size_t)(n0+srow)*K + scol;
  u16* lA = As + wave*1024;
  u16* lB = Bs + wave*1024;
  int q8 = (lane>>4)*8, r16 = lane&15;
  for (int k0=0; k0<K; k0+=32){
    async_ld16(gA + k0,                lA);
    async_ld16(gA + k0 + 16*(size_t)K, lA + 512);
    async_ld16(gB + k0,                lB);
    async_ld16(gB + k0 + 16*(size_t)K, lB + 512);
    __syncthreads();
    bf16x8 af[4], bfr[4];
    #pragma unroll
    for (int i=0;i<4;i++) af[i]  = *(const bf16x8*)&As[(wm + i*16 + r16)*32 + q8];
    #pragma unroll
    for (int j=0;j<4;j++) bfr[j] = *(const bf16x8*)&Bs[(wn + j*16 + r16)*32 + q8];
    #pragma unroll
    for (int i=0;i<4;i++)
      #pragma unroll
      for (int j=0;j<4;j++)
        acc[i][j] = __builtin_amdgcn_mfma_f32_16x16x32_bf16(af[i], bfr[j], acc[i][j], 0,0,0);
    __syncthreads();
  }
  #pragma unroll
  for (int i=0;i<4;i++){
    int row = m0 + wm + i*16 + (lane>>4)*4;
    #pragma unroll
    for (int j=0;j<4;j++){
      int col = n0 + wn + j*16 + r16;
      float bv = bias[col];
      #pragma unroll
      for (int r=0;r<4;r++){
        float val = acc[i][j][r] + bv;
        if (OB) ((u16*)Cv)[(size_t)(row+r)*N + col] = f2bf(val);
        else    ((float*)Cv)[(size_t)(row+r)*N + col] = val;
      }
    }
  }
}

// ---------------- K3: transform + transpose per (b,h,chunk) ----------------
// qb = (elu(q)+1)/8*e^c  row-major; kb = (elu(k)+1)*e^-c row-major; kt,vt transposed; ksc chunk sums
__global__ __launch_bounds__(256) void transform_kernel(const u16* __restrict__ qkvb,
    const float* __restrict__ cb, u16* __restrict__ qb, u16* __restrict__ kb,
    u16* __restrict__ kt, u16* __restrict__ vt, float* __restrict__ ksc)
{
  int bid = blockIdx.x;
  int bh = bid >> 6, ch = bid & 63;
  int b = bh >> 3, h = bh & 7;
  __shared__ u16 Ks[64*68];
  __shared__ u16 Vs[64*68];
  __shared__ float ksr[256];
  int t = threadIdx.x;
  size_t mbase = (size_t)b*L_ + ch*64;
  #pragma unroll
  for (int i=0;i<2;i++){
    int idx = t + 256*i;
    int l = idx>>3, e0 = (idx&7)*8;
    float c = cb[(size_t)bh*L_ + ch*64 + l];
    float eqc = expf(c)*0.125f, ekc = expf(-c);
    const u16* src = qkvb + (mbase+l)*TD + h*64 + e0;
    u16 in[8], o[8];
    // q
    *(ushort4*)&in[0] = *(const ushort4*)(src);
    *(ushort4*)&in[4] = *(const ushort4*)(src+4);
    #pragma unroll
    for (int j=0;j<8;j++) o[j] = f2bf(elu1(bf2f(in[j]))*eqc);
    u16* qdst = qb + (mbase+l)*D_ + h*64 + e0;
    *(ushort4*)qdst = *(ushort4*)&o[0];
    *(ushort4*)(qdst+4) = *(ushort4*)&o[4];
    // k
    *(ushort4*)&in[0] = *(const ushort4*)(src + D_);
    *(ushort4*)&in[4] = *(const ushort4*)(src + D_ + 4);
    #pragma unroll
    for (int j=0;j<8;j++) o[j] = f2bf(elu1(bf2f(in[j]))*ekc);
    u16* kdst = kb + (mbase+l)*D_ + h*64 + e0;
    *(ushort4*)kdst = *(ushort4*)&o[0];
    *(ushort4*)(kdst+4) = *(ushort4*)&o[4];
    *(ushort4*)&Ks[l*68+e0]   = *(ushort4*)&o[0];
    *(ushort4*)&Ks[l*68+e0+4] = *(ushort4*)&o[4];
    // v (copy bf16)
    *(ushort4*)&Vs[l*68+e0]   = *(const ushort4*)(src + 2*D_);
    *(ushort4*)&Vs[l*68+e0+4] = *(const ushort4*)(src + 2*D_ + 4);
  }
  __syncthreads();
  int e = t & 63, jq = t >> 6;
  float ksum = 0.f;
  u16 kv[16], vv[16];
  #pragma unroll
  for (int jj=0;jj<16;jj++){
    int j = jq*16+jj;
    kv[jj] = Ks[j*68 + e];
    ksum += bf2f(kv[jj]);
    vv[jj] = Vs[j*68 + e];
  }
  u16* kd = kt + ((size_t)bh*64 + e)*L_ + ch*64 + jq*16;
  u16* vd = vt + ((size_t)bh*64 + e)*L_ + ch*64 + jq*16;
  #pragma unroll
  for (int s=0;s<4;s++){
    *(ushort4*)(kd + s*4) = *(ushort4*)&kv[s*4];
    *(ushort4*)(vd + s*4) = *(ushort4*)&vv[s*4];
  }
  ksr[jq*64 + e] = ksum;
  __syncthreads();
  if (t < 64) ksc[bh*4096 + ch*64 + t] = ksr[t] + ksr[64+t] + ksr[128+t] + ksr[192+t];
}

// ---------------- K4: per-chunk S^T = V^T K~ via MFMA ----------------
__global__ __launch_bounds__(256) void chunk_sums_kernel(const u16* __restrict__ kt,
    const u16* __restrict__ vt, u16* __restrict__ Stc)
{
  int bid = blockIdx.x;
  int bh = bid >> 6, ch = bid & 63;
  __shared__ u16 KV[8192];          // Kl [kh][e][32] | Vl [kh][f][32]
  int t = threadIdx.x, w = t>>6, lane = t&63;
  #pragma unroll
  for (int q=0;q<4;q++){
    int i8 = (w*4+q)&7;
    int kh = i8>>2;
    int row = (i8&3)*16 + (lane>>2);
    int kl = (lane&3)*8;
    const u16* g = (w<2 ? kt : vt) + ((size_t)bh*64+row)*L_ + ch*64 + kh*32 + kl;
    async_ld16(g, KV + (w*4+q)*512);
  }
  __syncthreads();
  const u16* Kl = KV;
  const u16* Vl = KV + 4096;
  int r16 = lane & 15, q8 = (lane>>4)*8;
  bf16x8 av[2];
  #pragma unroll
  for (int kh=0;kh<2;kh++)
    av[kh] = *(const bf16x8*)&Vl[(kh*64 + w*16 + r16)*32 + q8];
  f32x4 acc[4] = {};
  #pragma unroll
  for (int et=0;et<4;et++)
    #pragma unroll
    for (int kh=0;kh<2;kh++){
      bf16x8 bv = *(const bf16x8*)&Kl[(kh*64 + et*16 + r16)*32 + q8];
      acc[et] = __builtin_amdgcn_mfma_f32_16x16x32_bf16(av[kh], bv, acc[et], 0,0,0);
    }
  #pragma unroll
  for (int et=0;et<4;et++)
    #pragma unroll
    for (int r=0;r<4;r++){
      int f = w*16 + (lane>>4)*4 + r;
      int e = et*16 + r16;
      Stc[(((size_t)bh*64 + ch)*64 + f)*64 + e] = f2bf(acc[et][r]);
    }
}

// ---------------- K5: exclusive prefix over chunks (in place, bf16 S / fp32 ksum) ----------------
__global__ __launch_bounds__(256) void chunk_prefix_kernel(u16* __restrict__ Stc,
    float* __restrict__ ksc)
{
  int gid = blockIdx.x*256 + threadIdx.x;   // 65536 threads
  int bh = gid >> 12, elem = gid & 4095;
  u16* p = Stc + (size_t)bh*262144 + elem;
  float run = 0.f;
  #pragma unroll 1
  for (int ch=0; ch<NCH; ch+=4){
    float v0 = bf2f(p[(ch+0)*4096]);
    float v1 = bf2f(p[(ch+1)*4096]);
    float v2 = bf2f(p[(ch+2)*4096]);
    float v3 = bf2f(p[(ch+3)*4096]);
    p[(ch+0)*4096] = f2bf(run); run += v0;
    p[(ch+1)*4096] = f2bf(run); run += v1;
    p[(ch+2)*4096] = f2bf(run); run += v2;
    p[(ch+3)*4096] = f2bf(run); run += v3;
  }
  if (gid < BH*64){
    int bh2 = gid >> 6, e = gid & 63;
    float* kp = ksc + bh2*4096 + e;
    float kr = 0.f;
    #pragma unroll 1
    for (int ch=0; ch<NCH; ch+=4){
      float v0=kp[(ch+0)*64], v1=kp[(ch+1)*64], v2=kp[(ch+2)*64], v3=kp[(ch+3)*64];
      kp[(ch+0)*64]=kr; kr+=v0; kp[(ch+1)*64]=kr; kr+=v1;
      kp[(ch+2)*64]=kr; kr+=v2; kp[(ch+3)*64]=kr; kr+=v3;
    }
  }
}

// ---------------- K6: chunk output via MFMA ----------------
__global__ __launch_bounds__(256) void chunk_out_kernel(const u16* __restrict__ qb,
    const u16* __restrict__ kb, const u16* __restrict__ vt,
    const u16* __restrict__ Stc, const float* __restrict__ ksc,
    u16* __restrict__ attn)
{
  int bid = blockIdx.x;
  int bh = bid >> 6, ch = bid & 63;
  int b = bh >> 3, h = bh & 7;
  __shared__ u16 KV[16384];     // Qs | Kb_s | Vt_s | St_s, each [kh][row][32]
  __shared__ u16 Ab[4096];      // [jh][l][32]
  __shared__ float kp[64], den4[256], den[64];
  int t = threadIdx.x, w = t>>6, lane = t&63;
  size_t mbase = (size_t)b*L_ + ch*64;
  // staging: wave w stages tile w
  #pragma unroll
  for (int q=0;q<8;q++){
    int kh = q>>2;
    int row = (q&3)*16 + (lane>>2);
    int kl = (lane&3)*8;
    const u16* g;
    if (w==0)      g = qb  + (mbase+row)*D_ + h*64 + kh*32 + kl;
    else if (w==1) g = kb  + (mbase+row)*D_ + h*64 + kh*32 + kl;
    else if (w==2) g = vt  + ((size_t)bh*64+row)*L_ + ch*64 + kh*32 + kl;
    else           g = Stc + (((size_t)bh*64+ch)*64 + row)*64 + kh*32 + kl;
    async_ld16(g, KV + w*4096 + q*512);
  }
  if (t < 64) kp[t] = ksc[bh*4096 + ch*64 + t];
  __syncthreads();   // B1
  const u16* Qs   = KV;
  const u16* Kb_s = KV + 4096;
  const u16* Vt_s = KV + 8192;
  const u16* St_s = KV + 12288;
  int r16 = lane & 15, q8 = (lane>>4)*8;
  // matmul1: A = Q~ K~^T  (strip l = w*16..w*16+15)
  bf16x8 aq[2];
  #pragma unroll
  for (int eh=0;eh<2;eh++)
    aq[eh] = *(const bf16x8*)&Qs[(eh*64 + w*16 + r16)*32 + q8];
  f32x4 accA[4] = {};
  #pragma unroll
  for (int jt=0;jt<4;jt++)
    #pragma unroll
    for (int eh=0;eh<2;eh++){
      bf16x8 bv = *(const bf16x8*)&Kb_s[(eh*64 + jt*16 + r16)*32 + q8];
      accA[jt] = __builtin_amdgcn_mfma_f32_16x16x32_bf16(aq[eh], bv, accA[jt], 0,0,0);
    }
  // den: q~ . kp part (needs only Qs, kp)
  int l4 = t>>2, q4 = t&3;
  float dkp = 0.f;
  {
    int eh = q4>>1, el0 = (q4&1)*16;
    bf16x8 x1 = *(const bf16x8*)&Qs[(eh*64 + l4)*32 + el0];
    bf16x8 x2 = *(const bf16x8*)&Qs[(eh*64 + l4)*32 + el0 + 8];
    #pragma unroll
    for (int i=0;i<8;i++)
      dkp += bf2f((u16)x1[i])*kp[q4*16+i] + bf2f((u16)x2[i])*kp[q4*16+8+i];
  }
  // mask + write A to LDS (bf16, split layout)
  #pragma unroll
  for (int jt=0;jt<4;jt++)
    #pragma unroll
    for (int r=0;r<4;r++){
      int lr = w*16 + ((lane>>4)<<2) + r;
      int j  = jt*16 + r16;
      Ab[((jt>>1)*64 + lr)*32 + (jt&1)*16 + r16] = (j <= lr) ? f2bf(accA[jt][r]) : (u16)0;
    }
  __syncthreads();   // B2: Ab visible
  // den: masked row-sum of A
  float dA = 0.f;
  {
    int jh2 = q4>>1, jl0 = (q4&1)*16;
    bf16x8 y1 = *(const bf16x8*)&Ab[(jh2*64 + l4)*32 + jl0];
    bf16x8 y2 = *(const bf16x8*)&Ab[(jh2*64 + l4)*32 + jl0 + 8];
    #pragma unroll
    for (int i=0;i<8;i++) dA += bf2f((u16)y1[i]) + bf2f((u16)y2[i]);
  }
  den4[t] = dkp + dA;
  __syncthreads();   // B3
  if (t < 64) den[t] = den4[t*4] + den4[t*4+1] + den4[t*4+2] + den4[t*4+3] + 1e-6f;
  // matmul2: num = A V + Q~ S^T
  bf16x8 aA[2];
  #pragma unroll
  for (int jh=0;jh<2;jh++)
    aA[jh] = *(const bf16x8*)&Ab[(jh*64 + w*16 + r16)*32 + q8];
  f32x4 acc[4] = {};
  #pragma unroll
  for (int ft=0;ft<4;ft++){
    #pragma unroll
    for (int jh=0;jh<2;jh++){
      bf16x8 bv = *(const bf16x8*)&Vt_s[(jh*64 + ft*16 + r16)*32 + q8];
      acc[ft] = __builtin_amdgcn_mfma_f32_16x16x32_bf16(aA[jh], bv, acc[ft], 0,0,0);
    }
    #pragma unroll
    for (int eh=0;eh<2;eh++){
      bf16x8 bv = *(const bf16x8*)&St_s[(eh*64 + ft*16 + r16)*32 + q8];
      acc[ft] = __builtin_amdgcn_mfma_f32_16x16x32_bf16(aq[eh], bv, acc[ft], 0,0,0);
    }
  }
  __syncthreads();   // B4: den visible
  float inv[4];
  #pragma unroll
  for (int r=0;r<4;r++) inv[r] = 1.f / den[w*16 + ((lane>>4)<<2) + r];
  #pragma unroll
  for (int ft=0;ft<4;ft++)
    #pragma unroll
    for (int r=0;r<4;r++){
      int lr = w*16 + ((lane>>4)<<2) + r;
      attn[(mbase + lr)*D_ + h*64 + ft*16 + r16] = f2bf(acc[ft][r]*inv[r]);
    }
}

// ---------------- K8: RMSNorm + scale ----------------
__global__ __launch_bounds__(256) void rmsnorm_kernel(const float* __restrict__ mid,
    const float* __restrict__ scale, float* __restrict__ out)
{
  int m = blockIdx.x, t = threadIdx.x;
  const float* row = mid + (size_t)m*D_;
  float v0 = row[t], v1 = row[t+256];
  float ss = v0*v0 + v1*v1;
  #pragma unroll
  for (int off=32; off>0; off>>=1) ss += __shfl_xor(ss, off);
  __shared__ float red[4];
  if ((t&63)==0) red[t>>6] = ss;
  __syncthreads();
  float tot = red[0]+red[1]+red[2]+red[3];
  float r = rsqrtf(tot*(1.f/512.f) + 1e-8f);
  out[(size_t)m*D_ + t]       = v0*r*scale[t];
  out[(size_t)m*D_ + t + 256] = v1*r*scale[t+256];
}

extern "C" void kernel_launch(void* const* d_in, const int* in_sizes, int n_in,
                              void* d_out, int out_size, void* d_ws, size_t ws_size,
                              hipStream_t stream)
{
  const float* x     = (const float*)d_in[0];
  const float* w_qkv = (const float*)d_in[1];
  const float* b_qkv = (const float*)d_in[2];
  const float* w_out = (const float*)d_in[3];
  const float* b_out = (const float*)d_in[4];
  const float* w_dec = (const float*)d_in[5];
  const float* b_dec = (const float*)d_in[6];
  const float* gnorm = (const float*)d_in[7];
  float* out = (float*)d_out;

  char* ws = (char*)d_ws;
  u16*   qkvb = (u16*)(ws);                    // 25,165,824  [M][1536] bf16 (mid fp32 reuses)
  u16*   qb   = (u16*)(ws + 25165824);         //  8,388,608
  u16*   kb   = (u16*)(ws + 33554432);         //  8,388,608
  u16*   kt   = (u16*)(ws + 41943040);         //  8,388,608  (attn reuses)
  u16*   vt   = (u16*)(ws + 50331648);         //  8,388,608
  u16*   Stc  = (u16*)(ws + 58720256);         //  8,388,608
  float* ksc  = (float*)(ws + 67108864);       //    262,144
  float* ll   = (float*)(ws + 67371008);       //    262,144
  float* cb   = (float*)(ws + 67633152);       //    262,144
  u16*   xb   = (u16*)(ws + 67895296);         //  8,388,608
  u16*   qwb  = (u16*)(ws + 76283904);         //  1,572,864
  u16*   owb  = (u16*)(ws + 77856768);         //    524,288  total 78,381,056
  float* mid  = (float*)(ws);
  u16*   attn = kt;

  convert_kernel<<<dim3(5120), dim3(256), 0, stream>>>(x, w_qkv, w_out, xb, qwb, owb);
  decay_ll_kernel<<<dim3(M_), dim3(64), 0, stream>>>(x, w_dec, b_dec, ll);
  scan_kernel<<<dim3(BH), dim3(1024), 0, stream>>>(ll, cb);
  gemm_mfma<true><<<dim3(TD/128, M_/128), dim3(256), 0, stream>>>(xb, qwb, b_qkv, qkvb, M_, TD, D_);
  transform_kernel<<<dim3(BH*NCH), dim3(256), 0, stream>>>(qkvb, cb, qb, kb, kt, vt, ksc);
  chunk_sums_kernel<<<dim3(BH*NCH), dim3(256), 0, stream>>>(kt, vt, Stc);
  chunk_prefix_kernel<<<dim3(256), dim3(256), 0, stream>>>(Stc, ksc);
  chunk_out_kernel<<<dim3(BH*NCH), dim3(256), 0, stream>>>(qb, kb, vt, Stc, ksc, attn);
  gemm_mfma<false><<<dim3(D_/128, M_/128), dim3(256), 0, stream>>>(attn, owb, b_out, mid, M_, D_, D_);
  rmsnorm_kernel<<<dim3(M_), dim3(256), 0, stream>>>(mid, gnorm, out);
}

// Round 7
// 171.984 us; speedup vs baseline: 2.8505x; 1.0784x over previous
//
#include <hip/hip_runtime.h>

typedef unsigned short u16;
typedef unsigned int u32;

#define B_ 2
#define L_ 4096
#define D_ 512
#define H_ 8
#define E_ 64
#define M_ (B_*L_)        // 8192 rows
#define TD (3*D_)         // 1536
#define NCH (L_/64)       // 64 chunks of 64 per sequence
#define BH (B_*H_)        // 16

typedef short bf16x8 __attribute__((ext_vector_type(8)));
typedef float f32x4 __attribute__((ext_vector_type(4)));

__device__ __forceinline__ float bf2f(u16 u){ return __uint_as_float(((u32)u)<<16); }
__device__ __forceinline__ u16 f2bf(float f){
  u32 u = __float_as_uint(f);
  u32 r = u + 0x7FFFu + ((u>>16)&1u);   // RNE; inputs finite
  return (u16)(r>>16);
}
__device__ __forceinline__ float elu1(float v){ return v>0.f ? v+1.f : expf(v); }

__device__ __forceinline__ void async_ld16(const u16* g, u16* l){
  __builtin_amdgcn_global_load_lds(
      (const __attribute__((address_space(1))) void*)g,
      (__attribute__((address_space(3))) void*)l, 16, 0, 0);
}

// ---------------- K1: decay logits + x->bf16 + weight conversions ----------------
// blocks 0..2047: 4 rows each (decay logits + xb);  blocks 2048..3071: qw/ow -> bf16
__global__ __launch_bounds__(256) void decay_conv_kernel(const float* __restrict__ x,
    const float* __restrict__ dw, const float* __restrict__ db,
    const float* __restrict__ qw, const float* __restrict__ ow,
    float* __restrict__ ll, u16* __restrict__ xb,
    u16* __restrict__ qwb, u16* __restrict__ owb)
{
  int blk = blockIdx.x;
  if (blk < 2048){
    int wv = threadIdx.x>>6, lane = threadIdx.x&63;
    int m = blk*4 + wv;
    float xr[8];
    #pragma unroll
    for (int i=0;i<8;i++) xr[i] = x[(size_t)m*D_ + lane + 64*i];
    #pragma unroll
    for (int i=0;i<8;i++) xb[(size_t)m*D_ + lane + 64*i] = f2bf(xr[i]);
    int b = m >> 12, l = m & (L_-1);
    for (int h=0; h<H_; h++){
      float acc = 0.f;
      #pragma unroll
      for (int i=0;i<8;i++) acc += xr[i]*dw[h*D_ + lane + 64*i];
      #pragma unroll
      for (int off=32; off>0; off>>=1) acc += __shfl_xor(acc, off);
      if (lane == h){
        float z = acc + db[h];
        float lam = 0.9f + 0.1f/(1.f + expf(-z));
        ll[((b*H_+h)*L_) + l] = logf(lam);
      }
    }
  } else {
    int gid = (blk-2048)*256 + threadIdx.x;   // 262144 float4 groups
    const float* src; u16* dst; int off;
    if (gid < 196608){ src = qw; dst = qwb; off = gid; }
    else { src = ow; dst = owb; off = gid - 196608; }
    float4 v = ((const float4*)src)[off];
    ushort4 o; o.x=f2bf(v.x); o.y=f2bf(v.y); o.z=f2bf(v.z); o.w=f2bf(v.w);
    ((ushort4*)dst)[off] = o;
  }
}

// ---------------- K2: inclusive scan over L (shfl-based), clip to [-50,50] ----------------
__global__ __launch_bounds__(256) void scan_kernel(const float* __restrict__ ll,
    float* __restrict__ cb)
{
  int bh = blockIdx.x, t = threadIdx.x;
  int lane = t & 63, wv = t >> 6;
  const float* p = ll + (size_t)bh*L_ + t*16;
  float s[16];
  #pragma unroll
  for (int q=0;q<4;q++){
    float4 v = *(const float4*)(p + q*4);
    s[q*4+0]=v.x; s[q*4+1]=v.y; s[q*4+2]=v.z; s[q*4+3]=v.w;
  }
  #pragma unroll
  for (int i=1;i<16;i++) s[i] += s[i-1];
  float tot = s[15];
  float ws = tot;
  #pragma unroll
  for (int off=1; off<64; off<<=1){
    float tmp = __shfl_up(ws, off);
    if (lane >= off) ws += tmp;
  }
  __shared__ float wsum[4];
  if (lane == 63) wsum[wv] = ws;
  __syncthreads();
  float base = 0.f;
  #pragma unroll
  for (int w2=0; w2<3; w2++) if (w2 < wv) base += wsum[w2];
  float ex = base + ws - tot;
  float* c = cb + (size_t)bh*L_ + t*16;
  #pragma unroll
  for (int i=0;i<16;i++) c[i] = fminf(50.f, fmaxf(-50.f, ex + s[i]));
}

// ---------------- MFMA GEMM: C[m][n] = sum_k A[m][k]*W[n][k] + bias[n] ----------------
template<bool OB>
__global__ __launch_bounds__(256) void gemm_mfma(const u16* __restrict__ A,
    const u16* __restrict__ W, const float* __restrict__ bias,
    void* __restrict__ Cv, int M, int N, int K)
{
  __shared__ u16 As[128*32];
  __shared__ u16 Bs[128*32];
  int n0 = blockIdx.x*128, m0 = blockIdx.y*128;
  int t = threadIdx.x, wave = t>>6, lane = t&63;
  int wm = (wave>>1)*64, wn = (wave&1)*64;
  f32x4 acc[4][4] = {};
  int srow = wave*32 + (lane>>2);
  int scol = (lane&3)*8;
  const u16* gA = A + (size_t)(m0+srow)*K + scol;
  const u16* gB = W + (size_t)(n0+srow)*K + scol;
  u16* lA = As + wave*1024;
  u16* lB = Bs + wave*1024;
  int q8 = (lane>>4)*8, r16 = lane&15;
  for (int k0=0; k0<K; k0+=32){
    async_ld16(gA + k0,                lA);
    async_ld16(gA + k0 + 16*(size_t)K, lA + 512);
    async_ld16(gB + k0,                lB);
    async_ld16(gB + k0 + 16*(size_t)K, lB + 512);
    __syncthreads();
    bf16x8 af[4], bfr[4];
    #pragma unroll
    for (int i=0;i<4;i++) af[i]  = *(const bf16x8*)&As[(wm + i*16 + r16)*32 + q8];
    #pragma unroll
    for (int j=0;j<4;j++) bfr[j] = *(const bf16x8*)&Bs[(wn + j*16 + r16)*32 + q8];
    #pragma unroll
    for (int i=0;i<4;i++)
      #pragma unroll
      for (int j=0;j<4;j++)
        acc[i][j] = __builtin_amdgcn_mfma_f32_16x16x32_bf16(af[i], bfr[j], acc[i][j], 0,0,0);
    __syncthreads();
  }
  #pragma unroll
  for (int i=0;i<4;i++){
    int row = m0 + wm + i*16 + (lane>>4)*4;
    #pragma unroll
    for (int j=0;j<4;j++){
      int col = n0 + wn + j*16 + r16;
      float bv = bias[col];
      #pragma unroll
      for (int r=0;r<4;r++){
        float val = acc[i][j][r] + bv;
        if (OB) ((u16*)Cv)[(size_t)(row+r)*N + col] = f2bf(val);
        else    ((float*)Cv)[(size_t)(row+r)*N + col] = val;
      }
    }
  }
}

// ---------------- K4: fused transform + transpose + chunk S^T MFMA ----------------
__global__ __launch_bounds__(256) void transform_sums_kernel(const u16* __restrict__ qkvb,
    const float* __restrict__ cb, u16* __restrict__ qc, u16* __restrict__ kc,
    u16* __restrict__ vtc, u16* __restrict__ Stc, float* __restrict__ ksc)
{
  int bid = blockIdx.x;
  int bh = bid >> 6, ch = bid & 63;
  int b = bh >> 3, h = bh & 7;
  __shared__ u16 Ks[64*68];
  __shared__ u16 Vs[64*68];
  __shared__ u16 Ktl[4096];
  __shared__ u16 Vtl[4096];
  __shared__ float ksr[256];
  int t = threadIdx.x;
  size_t mbase = (size_t)b*L_ + ch*64;
  #pragma unroll
  for (int i=0;i<2;i++){
    int idx = t + 256*i;
    int l = idx>>3, e0 = (idx&7)*8;
    int kh = e0>>5, ej = e0&31;
    float c = cb[(size_t)bh*L_ + ch*64 + l];
    float eqc = expf(c)*0.125f, ekc = expf(-c);
    const u16* src = qkvb + (mbase+l)*TD + h*64 + e0;
    u16 in[8], o[8];
    // q
    *(ushort4*)&in[0] = *(const ushort4*)(src);
    *(ushort4*)&in[4] = *(const ushort4*)(src+4);
    #pragma unroll
    for (int j=0;j<8;j++) o[j] = f2bf(elu1(bf2f(in[j]))*eqc);
    u16* qd = qc + ((size_t)bid*2 + kh)*2048 + l*32 + ej;
    *(ushort4*)qd = *(ushort4*)&o[0];
    *(ushort4*)(qd+4) = *(ushort4*)&o[4];
    // k
    *(ushort4*)&in[0] = *(const ushort4*)(src + D_);
    *(ushort4*)&in[4] = *(const ushort4*)(src + D_ + 4);
    #pragma unroll
    for (int j=0;j<8;j++) o[j] = f2bf(elu1(bf2f(in[j]))*ekc);
    u16* kd = kc + ((size_t)bid*2 + kh)*2048 + l*32 + ej;
    *(ushort4*)kd = *(ushort4*)&o[0];
    *(ushort4*)(kd+4) = *(ushort4*)&o[4];
    *(ushort4*)&Ks[l*68+e0]   = *(ushort4*)&o[0];
    *(ushort4*)&Ks[l*68+e0+4] = *(ushort4*)&o[4];
    // v
    *(ushort4*)&Vs[l*68+e0]   = *(const ushort4*)(src + 2*D_);
    *(ushort4*)&Vs[l*68+e0+4] = *(const ushort4*)(src + 2*D_ + 4);
  }
  __syncthreads();
  // transpose: thread (jq,e) -> K^T/V^T rows e, j in [jq*16, jq*16+16)
  int e = t & 63, jq = t >> 6;
  {
    u16 kv[16], vv[16];
    float ksum = 0.f;
    #pragma unroll
    for (int jj=0;jj<16;jj++){
      int j = jq*16+jj;
      kv[jj] = Ks[j*68 + e];
      ksum += bf2f(kv[jj]);
      vv[jj] = Vs[j*68 + e];
    }
    int kh = jq>>1, jl = (jq&1)*16;
    u16* kt = &Ktl[(kh*64 + e)*32 + jl];
    u16* vt = &Vtl[(kh*64 + e)*32 + jl];
    #pragma unroll
    for (int s=0;s<4;s++){
      *(ushort4*)(kt + s*4) = *(ushort4*)&kv[s*4];
      *(ushort4*)(vt + s*4) = *(ushort4*)&vv[s*4];
    }
    ksr[t] = ksum;
  }
  __syncthreads();
  // Vtl -> global (chunked layout) — FIXED: 2 x uint4 (8 u16 each) per thread covers all 4096
  {
    *(uint4*)&vtc[(size_t)bid*4096 + t*8]        = *(const uint4*)&Vtl[t*8];
    *(uint4*)&vtc[(size_t)bid*4096 + 2048 + t*8] = *(const uint4*)&Vtl[2048 + t*8];
  }
  // MFMA: St[f][e] = sum_j Vt[f][j] Kt[e][j]
  int w = t>>6, lane = t&63;
  int r16 = lane & 15, q8 = (lane>>4)*8;
  bf16x8 av[2];
  #pragma unroll
  for (int kh=0;kh<2;kh++)
    av[kh] = *(const bf16x8*)&Vtl[(kh*64 + w*16 + r16)*32 + q8];
  f32x4 acc[4] = {};
  #pragma unroll
  for (int et=0;et<4;et++)
    #pragma unroll
    for (int kh=0;kh<2;kh++){
      bf16x8 bv = *(const bf16x8*)&Ktl[(kh*64 + et*16 + r16)*32 + q8];
      acc[et] = __builtin_amdgcn_mfma_f32_16x16x32_bf16(av[kh], bv, acc[et], 0,0,0);
    }
  #pragma unroll
  for (int et=0;et<4;et++){
    int eh = et>>1, el = (et&1)*16 + r16;
    #pragma unroll
    for (int r=0;r<4;r++){
      int f = w*16 + (lane>>4)*4 + r;
      Stc[((size_t)bid*2 + eh)*2048 + f*32 + el] = f2bf(acc[et][r]);
    }
  }
  if (t < 64) ksc[bid*64 + t] = ksr[t] + ksr[64+t] + ksr[128+t] + ksr[192+t];
}

// ---------------- K5: exclusive prefix over chunks (u32-packed bf16 pairs) ----------------
__global__ __launch_bounds__(256) void chunk_prefix_kernel(u16* __restrict__ Stc,
    float* __restrict__ ksc)
{
  int gid = blockIdx.x*256 + threadIdx.x;   // 32768 threads (128 blocks)
  int bh = gid >> 11, e2 = gid & 2047;
  u32* p = (u32*)Stc + (size_t)bh*131072 + e2;
  float r0 = 0.f, r1 = 0.f;
  #pragma unroll 4
  for (int ch=0; ch<NCH; ch++){
    u32 v = p[ch*2048];
    float lo = bf2f((u16)(v & 0xffffu));
    float hi = bf2f((u16)(v >> 16));
    p[ch*2048] = (u32)f2bf(r0) | ((u32)f2bf(r1) << 16);
    r0 += lo; r1 += hi;
  }
  if (gid < BH*64){
    int bh2 = gid >> 6, e = gid & 63;
    float* kp = ksc + bh2*4096 + e;
    float kr = 0.f;
    #pragma unroll 4
    for (int ch=0; ch<NCH; ch++){
      float v = kp[ch*64]; kp[ch*64] = kr; kr += v;
    }
  }
}

// ---------------- K6: chunk output via MFMA (async chunked staging) ----------------
__global__ __launch_bounds__(256) void chunk_out_kernel(const u16* __restrict__ qc,
    const u16* __restrict__ kc, const u16* __restrict__ vtc,
    const u16* __restrict__ Stc, const float* __restrict__ ksc,
    u16* __restrict__ attn)
{
  int bid = blockIdx.x;
  int bh = bid >> 6, ch = bid & 63;
  int b = bh >> 3, h = bh & 7;
  __shared__ u16 KV[16384];     // Qs | Kb_s | Vt_s | St_s, each [half][row][32]
  __shared__ u16 Ab[4096];      // [jh][l][32]
  __shared__ float kp[64], den4[256], den[64];
  int t = threadIdx.x, w = t>>6, lane = t&63;
  size_t mbase = (size_t)b*L_ + ch*64;
  const u16* srcs[4] = { qc, kc, vtc, Stc };
  {
    const u16* gbase = srcs[w] + (size_t)bid*4096 + lane*8;
    #pragma unroll
    for (int q=0;q<8;q++)
      async_ld16(gbase + q*512, KV + w*4096 + q*512);
  }
  if (t < 64) kp[t] = ksc[bid*64 + t];
  __syncthreads();   // B1
  const u16* Qs   = KV;
  const u16* Kb_s = KV + 4096;
  const u16* Vt_s = KV + 8192;
  const u16* St_s = KV + 12288;
  int r16 = lane & 15, q8 = (lane>>4)*8;
  // matmul1: A = Q~ K~^T  (strip l = w*16..w*16+15)
  bf16x8 aq[2];
  #pragma unroll
  for (int eh=0;eh<2;eh++)
    aq[eh] = *(const bf16x8*)&Qs[(eh*64 + w*16 + r16)*32 + q8];
  f32x4 accA[4] = {};
  #pragma unroll
  for (int jt=0;jt<4;jt++)
    #pragma unroll
    for (int eh=0;eh<2;eh++){
      bf16x8 bv = *(const bf16x8*)&Kb_s[(eh*64 + jt*16 + r16)*32 + q8];
      accA[jt] = __builtin_amdgcn_mfma_f32_16x16x32_bf16(aq[eh], bv, accA[jt], 0,0,0);
    }
  // den: q~ . kp part
  int l4 = t>>2, q4 = t&3;
  float dkp = 0.f;
  {
    int eh = q4>>1, el0 = (q4&1)*16;
    bf16x8 x1 = *(const bf16x8*)&Qs[(eh*64 + l4)*32 + el0];
    bf16x8 x2 = *(const bf16x8*)&Qs[(eh*64 + l4)*32 + el0 + 8];
    #pragma unroll
    for (int i=0;i<8;i++)
      dkp += bf2f((u16)x1[i])*kp[q4*16+i] + bf2f((u16)x2[i])*kp[q4*16+8+i];
  }
  // mask + write A to LDS (bf16, split layout)
  #pragma unroll
  for (int jt=0;jt<4;jt++)
    #pragma unroll
    for (int r=0;r<4;r++){
      int lr = w*16 + ((lane>>4)<<2) + r;
      int j  = jt*16 + r16;
      Ab[((jt>>1)*64 + lr)*32 + (jt&1)*16 + r16] = (j <= lr) ? f2bf(accA[jt][r]) : (u16)0;
    }
  __syncthreads();   // B2
  // den: masked row-sum of A
  float dA = 0.f;
  {
    int jh2 = q4>>1, jl0 = (q4&1)*16;
    bf16x8 y1 = *(const bf16x8*)&Ab[(jh2*64 + l4)*32 + jl0];
    bf16x8 y2 = *(const bf16x8*)&Ab[(jh2*64 + l4)*32 + jl0 + 8];
    #pragma unroll
    for (int i=0;i<8;i++) dA += bf2f((u16)y1[i]) + bf2f((u16)y2[i]);
  }
  den4[t] = dkp + dA;
  __syncthreads();   // B3
  if (t < 64) den[t] = den4[t*4] + den4[t*4+1] + den4[t*4+2] + den4[t*4+3] + 1e-6f;
  // matmul2: num = A V + Q~ S^T
  bf16x8 aA[2];
  #pragma unroll
  for (int jh=0;jh<2;jh++)
    aA[jh] = *(const bf16x8*)&Ab[(jh*64 + w*16 + r16)*32 + q8];
  f32x4 acc[4] = {};
  #pragma unroll
  for (int ft=0;ft<4;ft++){
    #pragma unroll
    for (int jh=0;jh<2;jh++){
      bf16x8 bv = *(const bf16x8*)&Vt_s[(jh*64 + ft*16 + r16)*32 + q8];
      acc[ft] = __builtin_amdgcn_mfma_f32_16x16x32_bf16(aA[jh], bv, acc[ft], 0,0,0);
    }
    #pragma unroll
    for (int eh=0;eh<2;eh++){
      bf16x8 bv = *(const bf16x8*)&St_s[(eh*64 + ft*16 + r16)*32 + q8];
      acc[ft] = __builtin_amdgcn_mfma_f32_16x16x32_bf16(aq[eh], bv, acc[ft], 0,0,0);
    }
  }
  __syncthreads();   // B4
  float inv[4];
  #pragma unroll
  for (int r=0;r<4;r++) inv[r] = 1.f / den[w*16 + ((lane>>4)<<2) + r];
  #pragma unroll
  for (int ft=0;ft<4;ft++)
    #pragma unroll
    for (int r=0;r<4;r++){
      int lr = w*16 + ((lane>>4)<<2) + r;
      attn[(mbase + lr)*D_ + h*64 + ft*16 + r16] = f2bf(acc[ft][r]*inv[r]);
    }
}

// ---------------- K8: RMSNorm + scale (bf16 mid -> fp32 out) ----------------
__global__ __launch_bounds__(256) void rmsnorm_kernel(const u16* __restrict__ mid,
    const float* __restrict__ scale, float* __restrict__ out)
{
  int m = blockIdx.x, t = threadIdx.x;
  const u16* row = mid + (size_t)m*D_;
  float v0 = bf2f(row[t]), v1 = bf2f(row[t+256]);
  float ss = v0*v0 + v1*v1;
  #pragma unroll
  for (int off=32; off>0; off>>=1) ss += __shfl_xor(ss, off);
  __shared__ float red[4];
  if ((t&63)==0) red[t>>6] = ss;
  __syncthreads();
  float tot = red[0]+red[1]+red[2]+red[3];
  float r = rsqrtf(tot*(1.f/512.f) + 1e-8f);
  out[(size_t)m*D_ + t]       = v0*r*scale[t];
  out[(size_t)m*D_ + t + 256] = v1*r*scale[t+256];
}

extern "C" void kernel_launch(void* const* d_in, const int* in_sizes, int n_in,
                              void* d_out, int out_size, void* d_ws, size_t ws_size,
                              hipStream_t stream)
{
  const float* x     = (const float*)d_in[0];
  const float* w_qkv = (const float*)d_in[1];
  const float* b_qkv = (const float*)d_in[2];
  const float* w_out = (const float*)d_in[3];
  const float* b_out = (const float*)d_in[4];
  const float* w_dec = (const float*)d_in[5];
  const float* b_dec = (const float*)d_in[6];
  const float* gnorm = (const float*)d_in[7];
  float* out = (float*)d_out;

  char* ws = (char*)d_ws;
  u16*   qkvb = (u16*)(ws);                    // 25,165,824  [M][1536] bf16 (midb reuses)
  u16*   qc   = (u16*)(ws + 25165824);         //  8,388,608  chunked [bid][eh][l][32]
  u16*   kc   = (u16*)(ws + 33554432);         //  8,388,608  chunked [bid][eh][j][32]
  u16*   vtc  = (u16*)(ws + 41943040);         //  8,388,608  chunked [bid][jh][f][32]
  u16*   Stc  = (u16*)(ws + 50331648);         //  8,388,608  chunked [bid][eh][f][32]
  float* ksc  = (float*)(ws + 58720256);       //    262,144
  float* ll   = (float*)(ws + 58982400);       //    262,144
  float* cb   = (float*)(ws + 59244544);       //    262,144
  u16*   xb   = (u16*)(ws + 59506688);         //  8,388,608  (attn reuses after gemm_qkv)
  u16*   qwb  = (u16*)(ws + 67895296);         //  1,572,864
  u16*   owb  = (u16*)(ws + 69468160);         //    524,288  total 69,992,448
  u16*   midb = qkvb;                          // bf16 mid, reuses qkvb
  u16*   attn = xb;

  decay_conv_kernel<<<dim3(3072), dim3(256), 0, stream>>>(x, w_dec, b_dec, w_qkv, w_out,
                                                          ll, xb, qwb, owb);
  scan_kernel<<<dim3(BH), dim3(256), 0, stream>>>(ll, cb);
  gemm_mfma<true><<<dim3(TD/128, M_/128), dim3(256), 0, stream>>>(xb, qwb, b_qkv, qkvb, M_, TD, D_);
  transform_sums_kernel<<<dim3(BH*NCH), dim3(256), 0, stream>>>(qkvb, cb, qc, kc, vtc, Stc, ksc);
  chunk_prefix_kernel<<<dim3(128), dim3(256), 0, stream>>>(Stc, ksc);
  chunk_out_kernel<<<dim3(BH*NCH), dim3(256), 0, stream>>>(qc, kc, vtc, Stc, ksc, attn);
  gemm_mfma<true><<<dim3(D_/128, M_/128), dim3(256), 0, stream>>>(attn, owb, b_out, midb, M_, D_, D_);
  rmsnorm_kernel<<<dim3(M_), dim3(256), 0, stream>>>(midb, gnorm, out);
}